// Round 5
// baseline (279.614 us; speedup 1.0000x reference)
//
#include <hip/hip_runtime.h>
#include <hip/hip_bf16.h>

#define B_ 32
#define N_ 2048
#define D_ 512
#define KC_ 64
#define KG_ 80
#define M_ (B_*N_)   // 65536

typedef __attribute__((ext_vector_type(8))) short short8;
typedef __attribute__((ext_vector_type(4))) float f32x4;

// fp32 -> bf16 round-to-nearest-even, bit trick (finite inputs only)
__device__ __forceinline__ unsigned short bf_rn(float f){
  unsigned int u = __float_as_uint(f);
  unsigned int r = u + 0x7FFFu + ((u >> 16) & 1u);
  return (unsigned short)(r >> 16);
}
__device__ __forceinline__ float bf_up(unsigned short h){
  return __uint_as_float(((unsigned int)h) << 16);
}
// 8 fp32 -> hi/lo bf16 frags
__device__ __forceinline__ void cvt8(const float* v, short8& hi, short8& lo){
#pragma unroll
  for (int i=0;i<8;i++){
    unsigned short h = bf_rn(v[i]);
    float rem = v[i] - bf_up(h);
    hi[i] = (short)h;
    lo[i] = (short)bf_rn(rem);
  }
}

// ---------------- K0: clusters -> fragment-ordered bf16 hi/lo --------------
__global__ __launch_bounds__(256) void k0_prep(const float* __restrict__ cl,
                                               unsigned short* __restrict__ Bf)
{
  int tid = blockIdx.x*256 + threadIdx.x;     // 40*256 = 10240
  int l  = tid & 63;
  int hl = (tid >> 6) & 1;
  int j  = (tid >> 7) % 5;
  int c  = tid / 640;
  int kk  = c*32 + (l>>4)*8;
  int col = j*16 + (l&15);
  unsigned short o[8];
#pragma unroll
  for (int jj=0;jj<8;jj++){
    float v = cl[(size_t)(kk+jj)*KG_ + col];
    unsigned short h = bf_rn(v);
    if (hl == 0) o[jj] = h;
    else         o[jj] = bf_rn(v - bf_up(h));
  }
#pragma unroll
  for (int jj=0;jj<8;jj++) Bf[(size_t)tid*8 + jj] = o[jj];
}

// ---------------- K1: a = x @ clusters (MFMA, split-bf16) + col sums -------
// grid 1024 (64 rows/block), block 256 = 4 waves; wave: 16 rows x 80 cols.
// Software-pipelined: chunk c+1 x-loads issued before MFMA on chunk c.
// 4 blocks/CU (16 waves/CU) for latency hiding.
__global__ __launch_bounds__(256) void k1_proj(
    const float* __restrict__ x, const unsigned short* __restrict__ Bf,
    float* __restrict__ a, float* __restrict__ S1, float* __restrict__ S2)
{
  __shared__ float ls1[KG_], ls2[KG_];
  const int t = threadIdx.x;
  const int w = t >> 6, lane = t & 63;
  const int m = lane & 15, q = lane >> 4;
  const int row0 = blockIdx.x*64 + w*16;
  if (t < KG_){ ls1[t]=0.f; ls2[t]=0.f; }

  const float* xr = x + (size_t)(row0 + m)*D_ + q*8;

  f32x4 acc[5];
#pragma unroll
  for (int j=0;j<5;j++) acc[j] = (f32x4){0.f,0.f,0.f,0.f};

  float v[8], vn[8];
  *(float4*)&v[0] = *(const float4*)(xr);
  *(float4*)&v[4] = *(const float4*)(xr + 4);

  for (int c=0;c<16;c++){
    if (c < 15){                       // prefetch chunk c+1 while computing c
      *(float4*)&vn[0] = *(const float4*)(xr + (c+1)*32);
      *(float4*)&vn[4] = *(const float4*)(xr + (c+1)*32 + 4);
    }
    short8 ah, al;
    cvt8(v, ah, al);
    const unsigned short* bp = Bf + (size_t)(c*5)*1024 + lane*8;
#pragma unroll
    for (int j=0;j<5;j++){
      short8 bhi = *(const short8*)(bp + (size_t)j*1024);
      short8 blo = *(const short8*)(bp + (size_t)j*1024 + 512);
      acc[j] = __builtin_amdgcn_mfma_f32_16x16x32_bf16(ah, bhi, acc[j], 0,0,0);
      acc[j] = __builtin_amdgcn_mfma_f32_16x16x32_bf16(al, bhi, acc[j], 0,0,0);
      acc[j] = __builtin_amdgcn_mfma_f32_16x16x32_bf16(ah, blo, acc[j], 0,0,0);
    }
#pragma unroll
    for (int jj=0;jj<8;jj++) v[jj] = vn[jj];
  }

  // epilogue: store a + fused column sums
  float s1v[5], s2v[5];
#pragma unroll
  for (int j=0;j<5;j++){
    f32x4 vv = acc[j];
    size_t base = (size_t)(row0 + q*4)*KG_ + j*16 + m;
    a[base]        = vv[0];
    a[base+KG_]    = vv[1];
    a[base+2*KG_]  = vv[2];
    a[base+3*KG_]  = vv[3];
    s1v[j] = vv[0]+vv[1]+vv[2]+vv[3];
    s2v[j] = vv[0]*vv[0]+vv[1]*vv[1]+vv[2]*vv[2]+vv[3]*vv[3];
  }
#pragma unroll
  for (int j=0;j<5;j++){
    float s1 = s1v[j], s2 = s2v[j];
    s1 += __shfl_xor(s1,16); s1 += __shfl_xor(s1,32);
    s2 += __shfl_xor(s2,16); s2 += __shfl_xor(s2,32);
    if (q == 0){
      atomicAdd(&ls1[j*16+m], s1);
      atomicAdd(&ls2[j*16+m], s2);
    }
  }
  __syncthreads();
  if (t < KG_){ atomicAdd(&S1[t], ls1[t]); atomicAdd(&S2[t], ls2[t]); }
}

// ---------------- K3: fused BN finalize + affine + softmax -> packed bf16 --
__global__ __launch_bounds__(256) void k3_softmax(
    float* __restrict__ a, const float* __restrict__ S1, const float* __restrict__ S2,
    const float* __restrict__ gamma, const float* __restrict__ beta,
    float* __restrict__ asum)
{
  __shared__ float as[64*84];
  __shared__ float sc[KG_], sh[KG_];
  __shared__ float lsum[KC_];
  unsigned int* p32 = (unsigned int*)a;
  const int t = threadIdx.x;
  const int row0 = blockIdx.x * 64;
  if (t < KG_){
    const float invM = 1.0f / (float)M_;
    float mean = S1[t] * invM;
    float var  = S2[t] * invM - mean*mean;
    float scv = gamma[t] * rsqrtf(var + 1e-5f);
    sc[t] = scv;
    sh[t] = beta[t] - mean*scv;
  }
  if (t < KC_) lsum[t]=0.f;
  __syncthreads();
#pragma unroll
  for (int l=0;l<20;l++){
    int idx = t + 256*l;
    int r = idx/80, col = idx - r*80;
    float v = a[(size_t)(row0+r)*KG_ + col];
    as[r*84+col] = v*sc[col] + sh[col];
  }
  __syncthreads();
  const int rt = t >> 2;
  const int g  = t & 3;
  float m = -1e30f;
#pragma unroll
  for (int c=0;c<20;c++) m = fmaxf(m, as[rt*84 + g + 4*c]);
  m = fmaxf(m, __shfl_xor(m,1));
  m = fmaxf(m, __shfl_xor(m,2));
  float e[20]; float s = 0.f;
#pragma unroll
  for (int c=0;c<20;c++){ float v = __expf(as[rt*84 + g + 4*c] - m); e[c]=v; s+=v; }
  s += __shfl_xor(s,1);
  s += __shfl_xor(s,2);
  const float inv = 1.f/s;
#pragma unroll
  for (int c=0;c<16;c++){
    int col = g + 4*c;
    float pv = e[c]*inv;
    unsigned short h = bf_rn(pv);
    unsigned short lo = bf_rn(pv - bf_up(h));
    p32[(size_t)(row0+rt)*KG_ + col] = (unsigned int)h | ((unsigned int)lo << 16);
    float su = pv;
    su += __shfl_xor(su,4);  su += __shfl_xor(su,8);
    su += __shfl_xor(su,16); su += __shfl_xor(su,32);
    if ((t&63) < 4) atomicAdd(&lsum[col], su);
  }
  __syncthreads();
  if (t < KC_) atomicAdd(&asum[(blockIdx.x>>5)*KC_ + t], lsum[t]);
}

// ---------------- K4: vlad partials (MFMA, split-bf16) ---------------------
// grid 512: blk = dt*64 + b*2 + ns  (2 n-splits of 1024). block 256 = 4 waves.
// x A-frags in registers; only p is LDS-exchanged (conflict-free),
// double-buffered, one barrier per 32-n chunk. blk%8 invariant in dt ->
// the 8 dt-blocks sharing a p-slab land on one XCD (L2-local re-read).
__global__ __launch_bounds__(256,4) void k4_vlad(
    const float* __restrict__ x, const unsigned int* __restrict__ p32,
    float* __restrict__ vp)
{
  __shared__ unsigned short ph[2][2048], pl[2][2048];
  const int t = threadIdx.x;
  const int blk = blockIdx.x;
  const int dt  = blk >> 6;
  const int idx = blk & 63;
  const int b   = idx >> 1;
  const int ns  = idx & 1;
  const int w = t >> 6, lane = t & 63;
  const int m = lane & 15, q = lane >> 4;
  const int d0 = dt*64;
  const int nbase = ns*1024;

  const float*        xbase = x   + ((size_t)b*N_ + nbase + q*8)*D_  + d0 + w*16 + m;
  const unsigned int* pbase = p32 + ((size_t)b*N_ + nbase + q*8)*KG_ + w*16 + m;

  f32x4 acc[4];
#pragma unroll
  for (int j=0;j<4;j++) acc[j] = (f32x4){0.f,0.f,0.f,0.f};

  float v[8]; unsigned int u[8];
  short8 ahi, alo;
#pragma unroll
  for (int jj=0;jj<8;jj++) v[jj] = xbase[(size_t)jj*D_];
#pragma unroll
  for (int jj=0;jj<8;jj++) u[jj] = pbase[(size_t)jj*KG_];
  cvt8(v, ahi, alo);
  {
    short8 hp, lp;
#pragma unroll
    for (int jj=0;jj<8;jj++){ hp[jj] = (short)(u[jj] & 0xFFFFu); lp[jj] = (short)(u[jj] >> 16); }
    *(short8*)&ph[0][t*8] = hp;
    *(short8*)&pl[0][t*8] = lp;
  }

  int cur = 0;
  for (int c=0;c<32;c++){
    __syncthreads();
    if (c < 31){
      const float*        xp = xbase + (size_t)(c+1)*32*D_;
      const unsigned int* pp = pbase + (size_t)(c+1)*32*KG_;
#pragma unroll
      for (int jj=0;jj<8;jj++) v[jj] = xp[(size_t)jj*D_];
#pragma unroll
      for (int jj=0;jj<8;jj++) u[jj] = pp[(size_t)jj*KG_];
    }
#pragma unroll
    for (int j=0;j<4;j++){
      short8 bhi = *(const short8*)&ph[cur][(j*64+lane)*8];
      short8 blo = *(const short8*)&pl[cur][(j*64+lane)*8];
      acc[j] = __builtin_amdgcn_mfma_f32_16x16x32_bf16(ahi, bhi, acc[j], 0,0,0);
      acc[j] = __builtin_amdgcn_mfma_f32_16x16x32_bf16(alo, bhi, acc[j], 0,0,0);
      acc[j] = __builtin_amdgcn_mfma_f32_16x16x32_bf16(ahi, blo, acc[j], 0,0,0);
    }
    if (c < 31){
      cvt8(v, ahi, alo);
      short8 hp, lp;
#pragma unroll
      for (int jj=0;jj<8;jj++){ hp[jj] = (short)(u[jj] & 0xFFFFu); lp[jj] = (short)(u[jj] >> 16); }
      *(short8*)&ph[cur^1][t*8] = hp;
      *(short8*)&pl[cur^1][t*8] = lp;
    }
    cur ^= 1;
  }
#pragma unroll
  for (int j=0;j<4;j++){
    f32x4 vv = acc[j];
    size_t base = (((size_t)ns*B_ + b)*D_ + d0 + w*16 + q*4)*KC_ + j*16 + m;
    vp[base]         = vv[0];
    vp[base +   KC_] = vv[1];
    vp[base + 2*KC_] = vv[2];
    vp[base + 3*KC_] = vv[3];
  }
}

// ---------------- K5a: combine 2 splits + subtract + partial ssq -----------
__global__ __launch_bounds__(256) void k5a(
    const float* __restrict__ vp, const float* __restrict__ c2,
    const float* __restrict__ asum, float* __restrict__ vbuf,
    float* __restrict__ ssq)
{
  __shared__ float red[4][64];
  const int blk = blockIdx.x;
  const int b = blk >> 3, ds = blk & 7;
  const int t = threadIdx.x;
  const int k = t & 63, dg = t >> 6;
  const float av = asum[b*KC_ + k];
  const size_t stride = (size_t)B_*D_*KC_;
  float ss = 0.f;
#pragma unroll
  for (int s=0;s<16;s++){
    int d = ds*64 + dg + 4*s;
    size_t idx = ((size_t)b*D_ + d)*KC_ + k;
    float vv = vp[idx] + vp[idx+stride];
    vv -= c2[d*KC_ + k]*av;
    vbuf[idx] = vv;
    ss += vv*vv;
  }
  red[dg][k] = ss;
  __syncthreads();
  if (t < 64){
    float v = red[0][t] + red[1][t] + red[2][t] + red[3][t];
    atomicAdd(&ssq[b*KC_ + t], v);
  }
}

// ---------------- K5b: norms from ssq, scale, write out (full GPU) ---------
__global__ __launch_bounds__(256) void k5b(
    const float* __restrict__ vbuf, const float* __restrict__ ssq,
    float* __restrict__ out)
{
  __shared__ float invd[64];
  __shared__ float gi_s;
  const int blk = blockIdx.x;
  const int b = blk >> 3, ds = blk & 7;
  const int t = threadIdx.x;
  const int k = t & 63, dg = t >> 6;
  if (t < 64){
    float n2 = ssq[b*KC_ + t];
    float nn = sqrtf(n2);
    float denom = fmaxf(nn, 1e-12f);
    invd[t] = 1.f/denom;
    float ratio = nn/denom;
    float r2 = ratio*ratio;
#pragma unroll
    for (int mm=1;mm<64;mm<<=1) r2 += __shfl_xor(r2, mm);
    if (t==0){
      gi_s = 1.f/fmaxf(sqrtf(r2), 1e-12f);
    }
  }
  __syncthreads();
  const float gik = gi_s * invd[k];
#pragma unroll
  for (int s=0;s<16;s++){
    int d = ds*64 + dg + 4*s;
    size_t idx = ((size_t)b*D_ + d)*KC_ + k;
    out[idx] = vbuf[idx]*gik;
  }
}

extern "C" void kernel_launch(void* const* d_in, const int* in_sizes, int n_in,
                              void* d_out, int out_size, void* d_ws, size_t ws_size,
                              hipStream_t stream)
{
  const float* x     = (const float*)d_in[0];
  const float* cl    = (const float*)d_in[1];
  const float* c2    = (const float*)d_in[2];
  const float* gamma = (const float*)d_in[3];
  const float* beta  = (const float*)d_in[4];
  float* out = (float*)d_out;
  float* ws  = (float*)d_ws;

  // ws (floats): S1[80]@0  S2[80]@80  asum[2048]@160  ssq[2048]@2208
  //   (memset [0,4608))
  //   Bf (ushort 81920 = 40960 floats) @4608
  //   a [M*80] @45568  (p32 in-place after K3; vbuf reuse after K4)
  //   vp [2*B*D*KC] after a
  float* S1    = ws;
  float* S2    = ws + 80;
  float* asum  = ws + 160;
  float* ssq   = ws + 2208;
  unsigned short* Bf = (unsigned short*)(ws + 4608);
  float* a     = ws + 45568;
  float* vp    = a + (size_t)M_*KG_;

  hipMemsetAsync(ws, 0, 4608*sizeof(float), stream);
  k0_prep   <<<40,   256, 0, stream>>>(cl, Bf);
  k1_proj   <<<1024, 256, 0, stream>>>(x, Bf, a, S1, S2);
  k3_softmax<<<1024, 256, 0, stream>>>(a, S1, S2, gamma, beta, asum);
  k4_vlad   <<<512,  256, 0, stream>>>(x, (const unsigned int*)a, vp);
  k5a       <<<256,  256, 0, stream>>>(vp, c2, asum, a, ssq);
  k5b       <<<256,  256, 0, stream>>>(a, ssq, out);
}

// Round 6
// 273.319 us; speedup vs baseline: 1.0230x; 1.0230x over previous
//
#include <hip/hip_runtime.h>
#include <hip/hip_bf16.h>

#define B_ 32
#define N_ 2048
#define D_ 512
#define KC_ 64
#define KG_ 80
#define M_ (B_*N_)   // 65536

typedef __attribute__((ext_vector_type(8))) short short8;
typedef __attribute__((ext_vector_type(4))) float f32x4;

// fp32 -> bf16 round-to-nearest-even, bit trick (finite inputs only)
__device__ __forceinline__ unsigned short bf_rn(float f){
  unsigned int u = __float_as_uint(f);
  unsigned int r = u + 0x7FFFu + ((u >> 16) & 1u);
  return (unsigned short)(r >> 16);
}
__device__ __forceinline__ float bf_up(unsigned short h){
  return __uint_as_float(((unsigned int)h) << 16);
}
// 8 fp32 -> hi/lo bf16 frags
__device__ __forceinline__ void cvt8(const float* v, short8& hi, short8& lo){
#pragma unroll
  for (int i=0;i<8;i++){
    unsigned short h = bf_rn(v[i]);
    float rem = v[i] - bf_up(h);
    hi[i] = (short)h;
    lo[i] = (short)bf_rn(rem);
  }
}

// ---------------- K0: clusters -> fragment-ordered bf16 hi/lo --------------
__global__ __launch_bounds__(256) void k0_prep(const float* __restrict__ cl,
                                               unsigned short* __restrict__ Bf)
{
  int tid = blockIdx.x*256 + threadIdx.x;     // 40*256 = 10240
  int l  = tid & 63;
  int hl = (tid >> 6) & 1;
  int j  = (tid >> 7) % 5;
  int c  = tid / 640;
  int kk  = c*32 + (l>>4)*8;
  int col = j*16 + (l&15);
  unsigned short o[8];
#pragma unroll
  for (int jj=0;jj<8;jj++){
    float v = cl[(size_t)(kk+jj)*KG_ + col];
    unsigned short h = bf_rn(v);
    if (hl == 0) o[jj] = h;
    else         o[jj] = bf_rn(v - bf_up(h));
  }
#pragma unroll
  for (int jj=0;jj<8;jj++) Bf[(size_t)tid*8 + jj] = o[jj];
}

// ---------------- K1: a = x @ clusters (MFMA, split-bf16) + col sums -------
// grid 512 (128 rows), block 256 = 4 waves; wave: 32 rows (2 tiles) x 80 cols.
// Two independent row-tiles per wave (ILP) + register prefetch of chunk c+1's
// x during the 30-MFMA body of chunk c. (16-row/wave variant measured WORSE:
// 85us, MfmaUtil 7% — halves MFMA per Bf-load; do not shrink the tile.)
__global__ __launch_bounds__(256) void k1_proj(
    const float* __restrict__ x, const unsigned short* __restrict__ Bf,
    float* __restrict__ a, float* __restrict__ S1, float* __restrict__ S2)
{
  __shared__ float ls1[KG_], ls2[KG_];
  const int t = threadIdx.x;
  const int w = t >> 6, lane = t & 63;
  const int m = lane & 15, q = lane >> 4;
  const int row0 = blockIdx.x*128 + w*32;
  if (t < KG_){ ls1[t]=0.f; ls2[t]=0.f; }

  const float* xr0 = x + (size_t)(row0 + m)*D_ + q*8;
  const float* xr1 = xr0 + (size_t)16*D_;

  f32x4 acc[2][5];
#pragma unroll
  for (int rt=0;rt<2;rt++)
#pragma unroll
    for (int j=0;j<5;j++) acc[rt][j] = (f32x4){0.f,0.f,0.f,0.f};

  float v0[8], v1[8], vn0[8], vn1[8];
  *(float4*)&v0[0] = *(const float4*)(xr0);
  *(float4*)&v0[4] = *(const float4*)(xr0 + 4);
  *(float4*)&v1[0] = *(const float4*)(xr1);
  *(float4*)&v1[4] = *(const float4*)(xr1 + 4);

  for (int c=0;c<16;c++){
    if (c < 15){                 // prefetch chunk c+1 while MFMAs run on c
      *(float4*)&vn0[0] = *(const float4*)(xr0 + (c+1)*32);
      *(float4*)&vn0[4] = *(const float4*)(xr0 + (c+1)*32 + 4);
      *(float4*)&vn1[0] = *(const float4*)(xr1 + (c+1)*32);
      *(float4*)&vn1[4] = *(const float4*)(xr1 + (c+1)*32 + 4);
    }
    short8 ah0, al0, ah1, al1;
    cvt8(v0, ah0, al0);
    cvt8(v1, ah1, al1);
    const unsigned short* bp = Bf + (size_t)(c*5)*1024 + lane*8;
#pragma unroll
    for (int j=0;j<5;j++){
      short8 bhi = *(const short8*)(bp + (size_t)j*1024);
      short8 blo = *(const short8*)(bp + (size_t)j*1024 + 512);
      acc[0][j] = __builtin_amdgcn_mfma_f32_16x16x32_bf16(ah0, bhi, acc[0][j], 0,0,0);
      acc[0][j] = __builtin_amdgcn_mfma_f32_16x16x32_bf16(al0, bhi, acc[0][j], 0,0,0);
      acc[0][j] = __builtin_amdgcn_mfma_f32_16x16x32_bf16(ah0, blo, acc[0][j], 0,0,0);
      acc[1][j] = __builtin_amdgcn_mfma_f32_16x16x32_bf16(ah1, bhi, acc[1][j], 0,0,0);
      acc[1][j] = __builtin_amdgcn_mfma_f32_16x16x32_bf16(al1, bhi, acc[1][j], 0,0,0);
      acc[1][j] = __builtin_amdgcn_mfma_f32_16x16x32_bf16(ah1, blo, acc[1][j], 0,0,0);
    }
#pragma unroll
    for (int jj=0;jj<8;jj++){ v0[jj] = vn0[jj]; v1[jj] = vn1[jj]; }
  }

  // epilogue: store a + fused column sums
  float s1v[5] = {0,0,0,0,0}, s2v[5] = {0,0,0,0,0};
#pragma unroll
  for (int rt=0;rt<2;rt++){
#pragma unroll
    for (int j=0;j<5;j++){
      f32x4 v = acc[rt][j];
      size_t base = (size_t)(row0 + rt*16 + q*4)*KG_ + j*16 + m;
      a[base]        = v[0];
      a[base+KG_]    = v[1];
      a[base+2*KG_]  = v[2];
      a[base+3*KG_]  = v[3];
      s1v[j] += v[0]+v[1]+v[2]+v[3];
      s2v[j] += v[0]*v[0]+v[1]*v[1]+v[2]*v[2]+v[3]*v[3];
    }
  }
#pragma unroll
  for (int j=0;j<5;j++){
    float s1 = s1v[j], s2 = s2v[j];
    s1 += __shfl_xor(s1,16); s1 += __shfl_xor(s1,32);
    s2 += __shfl_xor(s2,16); s2 += __shfl_xor(s2,32);
    if (q == 0){
      atomicAdd(&ls1[j*16+m], s1);
      atomicAdd(&ls2[j*16+m], s2);
    }
  }
  __syncthreads();
  if (t < KG_){ atomicAdd(&S1[t], ls1[t]); atomicAdd(&S2[t], ls2[t]); }
}

// ---------------- K3: fused BN finalize + affine + softmax -> packed bf16 --
__global__ __launch_bounds__(256) void k3_softmax(
    float* __restrict__ a, const float* __restrict__ S1, const float* __restrict__ S2,
    const float* __restrict__ gamma, const float* __restrict__ beta,
    float* __restrict__ asum)
{
  __shared__ float as[64*84];
  __shared__ float sc[KG_], sh[KG_];
  __shared__ float lsum[KC_];
  unsigned int* p32 = (unsigned int*)a;
  const int t = threadIdx.x;
  const int row0 = blockIdx.x * 64;
  if (t < KG_){
    const float invM = 1.0f / (float)M_;
    float mean = S1[t] * invM;
    float var  = S2[t] * invM - mean*mean;
    float scv = gamma[t] * rsqrtf(var + 1e-5f);
    sc[t] = scv;
    sh[t] = beta[t] - mean*scv;
  }
  if (t < KC_) lsum[t]=0.f;
  __syncthreads();
#pragma unroll
  for (int l=0;l<20;l++){
    int idx = t + 256*l;
    int r = idx/80, col = idx - r*80;
    float v = a[(size_t)(row0+r)*KG_ + col];
    as[r*84+col] = v*sc[col] + sh[col];
  }
  __syncthreads();
  const int rt = t >> 2;
  const int g  = t & 3;
  float m = -1e30f;
#pragma unroll
  for (int c=0;c<20;c++) m = fmaxf(m, as[rt*84 + g + 4*c]);
  m = fmaxf(m, __shfl_xor(m,1));
  m = fmaxf(m, __shfl_xor(m,2));
  float e[20]; float s = 0.f;
#pragma unroll
  for (int c=0;c<20;c++){ float v = __expf(as[rt*84 + g + 4*c] - m); e[c]=v; s+=v; }
  s += __shfl_xor(s,1);
  s += __shfl_xor(s,2);
  const float inv = 1.f/s;
#pragma unroll
  for (int c=0;c<16;c++){
    int col = g + 4*c;
    float pv = e[c]*inv;
    unsigned short h = bf_rn(pv);
    unsigned short lo = bf_rn(pv - bf_up(h));
    p32[(size_t)(row0+rt)*KG_ + col] = (unsigned int)h | ((unsigned int)lo << 16);
    float su = pv;
    su += __shfl_xor(su,4);  su += __shfl_xor(su,8);
    su += __shfl_xor(su,16); su += __shfl_xor(su,32);
    if ((t&63) < 4) atomicAdd(&lsum[col], su);
  }
  __syncthreads();
  if (t < KC_) atomicAdd(&asum[(blockIdx.x>>5)*KC_ + t], lsum[t]);
}

// ---------------- K4: vlad partials (MFMA, split-bf16) ---------------------
// grid 512: blk = dt*64 + b*2 + ns  (2 n-splits of 1024). block 256 = 4 waves.
// x A-frags in registers; only p is LDS-exchanged (conflict-free),
// double-buffered, one barrier per 32-n chunk. blk%8 invariant in dt ->
// the 8 dt-blocks sharing a p-slab land on one XCD (L2-local re-read).
__global__ __launch_bounds__(256,4) void k4_vlad(
    const float* __restrict__ x, const unsigned int* __restrict__ p32,
    float* __restrict__ vp)
{
  __shared__ unsigned short ph[2][2048], pl[2][2048];
  const int t = threadIdx.x;
  const int blk = blockIdx.x;
  const int dt  = blk >> 6;
  const int idx = blk & 63;
  const int b   = idx >> 1;
  const int ns  = idx & 1;
  const int w = t >> 6, lane = t & 63;
  const int m = lane & 15, q = lane >> 4;
  const int d0 = dt*64;
  const int nbase = ns*1024;

  const float*        xbase = x   + ((size_t)b*N_ + nbase + q*8)*D_  + d0 + w*16 + m;
  const unsigned int* pbase = p32 + ((size_t)b*N_ + nbase + q*8)*KG_ + w*16 + m;

  f32x4 acc[4];
#pragma unroll
  for (int j=0;j<4;j++) acc[j] = (f32x4){0.f,0.f,0.f,0.f};

  float v[8]; unsigned int u[8];
  short8 ahi, alo;
#pragma unroll
  for (int jj=0;jj<8;jj++) v[jj] = xbase[(size_t)jj*D_];
#pragma unroll
  for (int jj=0;jj<8;jj++) u[jj] = pbase[(size_t)jj*KG_];
  cvt8(v, ahi, alo);
  {
    short8 hp, lp;
#pragma unroll
    for (int jj=0;jj<8;jj++){ hp[jj] = (short)(u[jj] & 0xFFFFu); lp[jj] = (short)(u[jj] >> 16); }
    *(short8*)&ph[0][t*8] = hp;
    *(short8*)&pl[0][t*8] = lp;
  }

  int cur = 0;
  for (int c=0;c<32;c++){
    __syncthreads();
    if (c < 31){
      const float*        xp = xbase + (size_t)(c+1)*32*D_;
      const unsigned int* pp = pbase + (size_t)(c+1)*32*KG_;
#pragma unroll
      for (int jj=0;jj<8;jj++) v[jj] = xp[(size_t)jj*D_];
#pragma unroll
      for (int jj=0;jj<8;jj++) u[jj] = pp[(size_t)jj*KG_];
    }
#pragma unroll
    for (int j=0;j<4;j++){
      short8 bhi = *(const short8*)&ph[cur][(j*64+lane)*8];
      short8 blo = *(const short8*)&pl[cur][(j*64+lane)*8];
      acc[j] = __builtin_amdgcn_mfma_f32_16x16x32_bf16(ahi, bhi, acc[j], 0,0,0);
      acc[j] = __builtin_amdgcn_mfma_f32_16x16x32_bf16(alo, bhi, acc[j], 0,0,0);
      acc[j] = __builtin_amdgcn_mfma_f32_16x16x32_bf16(ahi, blo, acc[j], 0,0,0);
    }
    if (c < 31){
      cvt8(v, ahi, alo);
      short8 hp, lp;
#pragma unroll
      for (int jj=0;jj<8;jj++){ hp[jj] = (short)(u[jj] & 0xFFFFu); lp[jj] = (short)(u[jj] >> 16); }
      *(short8*)&ph[cur^1][t*8] = hp;
      *(short8*)&pl[cur^1][t*8] = lp;
    }
    cur ^= 1;
  }
#pragma unroll
  for (int j=0;j<4;j++){
    f32x4 vv = acc[j];
    size_t base = (((size_t)ns*B_ + b)*D_ + d0 + w*16 + q*4)*KC_ + j*16 + m;
    vp[base]         = vv[0];
    vp[base +   KC_] = vv[1];
    vp[base + 2*KC_] = vv[2];
    vp[base + 3*KC_] = vv[3];
  }
}

// ---------------- K5a: combine 2 splits + subtract + partial ssq -----------
__global__ __launch_bounds__(256) void k5a(
    const float* __restrict__ vp, const float* __restrict__ c2,
    const float* __restrict__ asum, float* __restrict__ vbuf,
    float* __restrict__ ssq)
{
  __shared__ float red[4][64];
  const int blk = blockIdx.x;
  const int b = blk >> 3, ds = blk & 7;
  const int t = threadIdx.x;
  const int k = t & 63, dg = t >> 6;
  const float av = asum[b*KC_ + k];
  const size_t stride = (size_t)B_*D_*KC_;
  float ss = 0.f;
#pragma unroll
  for (int s=0;s<16;s++){
    int d = ds*64 + dg + 4*s;
    size_t idx = ((size_t)b*D_ + d)*KC_ + k;
    float vv = vp[idx] + vp[idx+stride];
    vv -= c2[d*KC_ + k]*av;
    vbuf[idx] = vv;
    ss += vv*vv;
  }
  red[dg][k] = ss;
  __syncthreads();
  if (t < 64){
    float v = red[0][t] + red[1][t] + red[2][t] + red[3][t];
    atomicAdd(&ssq[b*KC_ + t], v);
  }
}

// ---------------- K5b: norms from ssq, scale, write out (full GPU) ---------
__global__ __launch_bounds__(256) void k5b(
    const float* __restrict__ vbuf, const float* __restrict__ ssq,
    float* __restrict__ out)
{
  __shared__ float invd[64];
  __shared__ float gi_s;
  const int blk = blockIdx.x;
  const int b = blk >> 3, ds = blk & 7;
  const int t = threadIdx.x;
  const int k = t & 63, dg = t >> 6;
  if (t < 64){
    float n2 = ssq[b*KC_ + t];
    float nn = sqrtf(n2);
    float denom = fmaxf(nn, 1e-12f);
    invd[t] = 1.f/denom;
    float ratio = nn/denom;
    float r2 = ratio*ratio;
#pragma unroll
    for (int mm=1;mm<64;mm<<=1) r2 += __shfl_xor(r2, mm);
    if (t==0){
      gi_s = 1.f/fmaxf(sqrtf(r2), 1e-12f);
    }
  }
  __syncthreads();
  const float gik = gi_s * invd[k];
#pragma unroll
  for (int s=0;s<16;s++){
    int d = ds*64 + dg + 4*s;
    size_t idx = ((size_t)b*D_ + d)*KC_ + k;
    out[idx] = vbuf[idx]*gik;
  }
}

extern "C" void kernel_launch(void* const* d_in, const int* in_sizes, int n_in,
                              void* d_out, int out_size, void* d_ws, size_t ws_size,
                              hipStream_t stream)
{
  const float* x     = (const float*)d_in[0];
  const float* cl    = (const float*)d_in[1];
  const float* c2    = (const float*)d_in[2];
  const float* gamma = (const float*)d_in[3];
  const float* beta  = (const float*)d_in[4];
  float* out = (float*)d_out;
  float* ws  = (float*)d_ws;

  // ws (floats): S1[80]@0  S2[80]@80  asum[2048]@160  ssq[2048]@2208
  //   (memset [0,4608))
  //   Bf (ushort 81920 = 40960 floats) @4608
  //   a [M*80] @45568  (p32 in-place after K3; vbuf reuse after K4)
  //   vp [2*B*D*KC] after a
  float* S1    = ws;
  float* S2    = ws + 80;
  float* asum  = ws + 160;
  float* ssq   = ws + 2208;
  unsigned short* Bf = (unsigned short*)(ws + 4608);
  float* a     = ws + 45568;
  float* vp    = a + (size_t)M_*KG_;

  hipMemsetAsync(ws, 0, 4608*sizeof(float), stream);
  k0_prep   <<<40,   256, 0, stream>>>(cl, Bf);
  k1_proj   <<<512,  256, 0, stream>>>(x, Bf, a, S1, S2);
  k3_softmax<<<1024, 256, 0, stream>>>(a, S1, S2, gamma, beta, asum);
  k4_vlad   <<<512,  256, 0, stream>>>(x, (const unsigned int*)a, vp);
  k5a       <<<256,  256, 0, stream>>>(vp, c2, asum, a, ssq);
  k5b       <<<256,  256, 0, stream>>>(a, ssq, out);
}

// Round 7
// 258.808 us; speedup vs baseline: 1.0804x; 1.0561x over previous
//
#include <hip/hip_runtime.h>
#include <hip/hip_bf16.h>

#define B_ 32
#define N_ 2048
#define D_ 512
#define KC_ 64
#define KG_ 80
#define M_ (B_*N_)   // 65536

typedef __attribute__((ext_vector_type(8))) short short8;
typedef __attribute__((ext_vector_type(4))) float f32x4;

// fp32 -> bf16 round-to-nearest-even, bit trick (finite inputs only)
__device__ __forceinline__ unsigned short bf_rn(float f){
  unsigned int u = __float_as_uint(f);
  unsigned int r = u + 0x7FFFu + ((u >> 16) & 1u);
  return (unsigned short)(r >> 16);
}
__device__ __forceinline__ float bf_up(unsigned short h){
  return __uint_as_float(((unsigned int)h) << 16);
}
// 8 fp32 -> hi/lo bf16 frags
__device__ __forceinline__ void cvt8(const float* v, short8& hi, short8& lo){
#pragma unroll
  for (int i=0;i<8;i++){
    unsigned short h = bf_rn(v[i]);
    float rem = v[i] - bf_up(h);
    hi[i] = (short)h;
    lo[i] = (short)bf_rn(rem);
  }
}

// ---------------- K0: clusters -> fragment-ordered bf16 hi/lo --------------
__global__ __launch_bounds__(256) void k0_prep(const float* __restrict__ cl,
                                               unsigned short* __restrict__ Bf)
{
  int tid = blockIdx.x*256 + threadIdx.x;     // 40*256 = 10240
  int l  = tid & 63;
  int hl = (tid >> 6) & 1;
  int j  = (tid >> 7) % 5;
  int c  = tid / 640;
  int kk  = c*32 + (l>>4)*8;
  int col = j*16 + (l&15);
  unsigned short o[8];
#pragma unroll
  for (int jj=0;jj<8;jj++){
    float v = cl[(size_t)(kk+jj)*KG_ + col];
    unsigned short h = bf_rn(v);
    if (hl == 0) o[jj] = h;
    else         o[jj] = bf_rn(v - bf_up(h));
  }
#pragma unroll
  for (int jj=0;jj<8;jj++) Bf[(size_t)tid*8 + jj] = o[jj];
}

// ---------------- K1: a = x @ clusters (MFMA, split-bf16) + col sums -------
// grid 512 (128 rows), block 256 = 4 waves; wave: 32 rows (2 tiles) x 80 cols.
// k4-style pipeline: Bf chunk (10KB) double-buffered through LDS so the MFMA
// j-loop consumes ONLY lgkmcnt (ds_read) + registers — no vmcnt waits inside.
// x chunk prefetched in registers; all vmcnt waits land once per iter, after
// the MFMA body. (Previous version had Bf global loads in the j-loop sharing
// the vmcnt queue with the HBM x-prefetch: every MFMA cluster stalled behind
// the x stream -> 78us, MfmaUtil 7.7%, HBM 14%.)
__global__ __launch_bounds__(256) void k1_proj(
    const float* __restrict__ x, const unsigned int* __restrict__ Bf32,
    float* __restrict__ a, float* __restrict__ S1, float* __restrict__ S2)
{
  __shared__ unsigned int bbuf[2][2560];   // 2 x 10KB Bf chunk
  __shared__ float ls1[KG_], ls2[KG_];
  const int t = threadIdx.x;
  const int w = t >> 6, lane = t & 63;
  const int m = lane & 15, q = lane >> 4;
  const int row0 = blockIdx.x*128 + w*32;
  if (t < KG_){ ls1[t]=0.f; ls2[t]=0.f; }

  const float* xr0 = x + (size_t)(row0 + m)*D_ + q*8;
  const float* xr1 = xr0 + (size_t)16*D_;

  f32x4 acc[2][5];
#pragma unroll
  for (int rt=0;rt<2;rt++)
#pragma unroll
    for (int j=0;j<5;j++) acc[rt][j] = (f32x4){0.f,0.f,0.f,0.f};

  float v0[8], v1[8], vn0[8], vn1[8];
  unsigned int un[10];
  // prologue: x chunk 0 -> regs; Bf chunk 0 -> LDS buf 0
  *(float4*)&v0[0] = *(const float4*)(xr0);
  *(float4*)&v0[4] = *(const float4*)(xr0 + 4);
  *(float4*)&v1[0] = *(const float4*)(xr1);
  *(float4*)&v1[4] = *(const float4*)(xr1 + 4);
#pragma unroll
  for (int i=0;i<10;i++) un[i] = Bf32[t + 256*i];
#pragma unroll
  for (int i=0;i<10;i++) bbuf[0][t + 256*i] = un[i];

  int cur = 0;
  for (int c=0;c<16;c++){
    __syncthreads();                 // buf[cur] staged; prior reads of buf[cur^1] done
    if (c < 15){                     // prefetch chunk c+1 (x -> regs, Bf -> regs)
      *(float4*)&vn0[0] = *(const float4*)(xr0 + (c+1)*32);
      *(float4*)&vn0[4] = *(const float4*)(xr0 + (c+1)*32 + 4);
      *(float4*)&vn1[0] = *(const float4*)(xr1 + (c+1)*32);
      *(float4*)&vn1[4] = *(const float4*)(xr1 + (c+1)*32 + 4);
      const unsigned int* bp = Bf32 + (size_t)(c+1)*2560 + t;
#pragma unroll
      for (int i=0;i<10;i++) un[i] = bp[256*i];
    }
    short8 ah0, al0, ah1, al1;
    cvt8(v0, ah0, al0);
    cvt8(v1, ah1, al1);
    const unsigned short* bs = (const unsigned short*)bbuf[cur];
#pragma unroll
    for (int j=0;j<5;j++){
      short8 bhi = *(const short8*)(bs + j*1024 + lane*8);
      short8 blo = *(const short8*)(bs + j*1024 + 512 + lane*8);
      acc[0][j] = __builtin_amdgcn_mfma_f32_16x16x32_bf16(ah0, bhi, acc[0][j], 0,0,0);
      acc[0][j] = __builtin_amdgcn_mfma_f32_16x16x32_bf16(al0, bhi, acc[0][j], 0,0,0);
      acc[0][j] = __builtin_amdgcn_mfma_f32_16x16x32_bf16(ah0, blo, acc[0][j], 0,0,0);
      acc[1][j] = __builtin_amdgcn_mfma_f32_16x16x32_bf16(ah1, bhi, acc[1][j], 0,0,0);
      acc[1][j] = __builtin_amdgcn_mfma_f32_16x16x32_bf16(al1, bhi, acc[1][j], 0,0,0);
      acc[1][j] = __builtin_amdgcn_mfma_f32_16x16x32_bf16(ah1, blo, acc[1][j], 0,0,0);
    }
    if (c < 15){                     // stage Bf c+1 -> buf[cur^1]; roll x regs
#pragma unroll
      for (int i=0;i<10;i++) bbuf[cur^1][t + 256*i] = un[i];
#pragma unroll
      for (int jj=0;jj<8;jj++){ v0[jj] = vn0[jj]; v1[jj] = vn1[jj]; }
    }
    cur ^= 1;
  }

  // epilogue: store a + fused column sums
  float s1v[5] = {0,0,0,0,0}, s2v[5] = {0,0,0,0,0};
#pragma unroll
  for (int rt=0;rt<2;rt++){
#pragma unroll
    for (int j=0;j<5;j++){
      f32x4 v = acc[rt][j];
      size_t base = (size_t)(row0 + rt*16 + q*4)*KG_ + j*16 + m;
      a[base]        = v[0];
      a[base+KG_]    = v[1];
      a[base+2*KG_]  = v[2];
      a[base+3*KG_]  = v[3];
      s1v[j] += v[0]+v[1]+v[2]+v[3];
      s2v[j] += v[0]*v[0]+v[1]*v[1]+v[2]*v[2]+v[3]*v[3];
    }
  }
#pragma unroll
  for (int j=0;j<5;j++){
    float s1 = s1v[j], s2 = s2v[j];
    s1 += __shfl_xor(s1,16); s1 += __shfl_xor(s1,32);
    s2 += __shfl_xor(s2,16); s2 += __shfl_xor(s2,32);
    if (q == 0){
      atomicAdd(&ls1[j*16+m], s1);
      atomicAdd(&ls2[j*16+m], s2);
    }
  }
  __syncthreads();
  if (t < KG_){ atomicAdd(&S1[t], ls1[t]); atomicAdd(&S2[t], ls2[t]); }
}

// ---------------- K3: fused BN finalize + affine + softmax -> packed bf16 --
__global__ __launch_bounds__(256) void k3_softmax(
    float* __restrict__ a, const float* __restrict__ S1, const float* __restrict__ S2,
    const float* __restrict__ gamma, const float* __restrict__ beta,
    float* __restrict__ asum)
{
  __shared__ float as[64*84];
  __shared__ float sc[KG_], sh[KG_];
  __shared__ float lsum[KC_];
  unsigned int* p32 = (unsigned int*)a;
  const int t = threadIdx.x;
  const int row0 = blockIdx.x * 64;
  if (t < KG_){
    const float invM = 1.0f / (float)M_;
    float mean = S1[t] * invM;
    float var  = S2[t] * invM - mean*mean;
    float scv = gamma[t] * rsqrtf(var + 1e-5f);
    sc[t] = scv;
    sh[t] = beta[t] - mean*scv;
  }
  if (t < KC_) lsum[t]=0.f;
  __syncthreads();
#pragma unroll
  for (int l=0;l<20;l++){
    int idx = t + 256*l;
    int r = idx/80, col = idx - r*80;
    float v = a[(size_t)(row0+r)*KG_ + col];
    as[r*84+col] = v*sc[col] + sh[col];
  }
  __syncthreads();
  const int rt = t >> 2;
  const int g  = t & 3;
  float m = -1e30f;
#pragma unroll
  for (int c=0;c<20;c++) m = fmaxf(m, as[rt*84 + g + 4*c]);
  m = fmaxf(m, __shfl_xor(m,1));
  m = fmaxf(m, __shfl_xor(m,2));
  float e[20]; float s = 0.f;
#pragma unroll
  for (int c=0;c<20;c++){ float v = __expf(as[rt*84 + g + 4*c] - m); e[c]=v; s+=v; }
  s += __shfl_xor(s,1);
  s += __shfl_xor(s,2);
  const float inv = 1.f/s;
#pragma unroll
  for (int c=0;c<16;c++){
    int col = g + 4*c;
    float pv = e[c]*inv;
    unsigned short h = bf_rn(pv);
    unsigned short lo = bf_rn(pv - bf_up(h));
    p32[(size_t)(row0+rt)*KG_ + col] = (unsigned int)h | ((unsigned int)lo << 16);
    float su = pv;
    su += __shfl_xor(su,4);  su += __shfl_xor(su,8);
    su += __shfl_xor(su,16); su += __shfl_xor(su,32);
    if ((t&63) < 4) atomicAdd(&lsum[col], su);
  }
  __syncthreads();
  if (t < KC_) atomicAdd(&asum[(blockIdx.x>>5)*KC_ + t], lsum[t]);
}

// ---------------- K4: vlad partials (MFMA, split-bf16) ---------------------
// grid 512: blk = dt*64 + b*2 + ns  (2 n-splits of 1024). block 256 = 4 waves.
// x A-frags in registers; only p is LDS-exchanged (conflict-free),
// double-buffered, one barrier per 32-n chunk. blk%8 invariant in dt ->
// the 8 dt-blocks sharing a p-slab land on one XCD (L2-local re-read).
__global__ __launch_bounds__(256,4) void k4_vlad(
    const float* __restrict__ x, const unsigned int* __restrict__ p32,
    float* __restrict__ vp)
{
  __shared__ unsigned short ph[2][2048], pl[2][2048];
  const int t = threadIdx.x;
  const int blk = blockIdx.x;
  const int dt  = blk >> 6;
  const int idx = blk & 63;
  const int b   = idx >> 1;
  const int ns  = idx & 1;
  const int w = t >> 6, lane = t & 63;
  const int m = lane & 15, q = lane >> 4;
  const int d0 = dt*64;
  const int nbase = ns*1024;

  const float*        xbase = x   + ((size_t)b*N_ + nbase + q*8)*D_  + d0 + w*16 + m;
  const unsigned int* pbase = p32 + ((size_t)b*N_ + nbase + q*8)*KG_ + w*16 + m;

  f32x4 acc[4];
#pragma unroll
  for (int j=0;j<4;j++) acc[j] = (f32x4){0.f,0.f,0.f,0.f};

  float v[8]; unsigned int u[8];
  short8 ahi, alo;
#pragma unroll
  for (int jj=0;jj<8;jj++) v[jj] = xbase[(size_t)jj*D_];
#pragma unroll
  for (int jj=0;jj<8;jj++) u[jj] = pbase[(size_t)jj*KG_];
  cvt8(v, ahi, alo);
  {
    short8 hp, lp;
#pragma unroll
    for (int jj=0;jj<8;jj++){ hp[jj] = (short)(u[jj] & 0xFFFFu); lp[jj] = (short)(u[jj] >> 16); }
    *(short8*)&ph[0][t*8] = hp;
    *(short8*)&pl[0][t*8] = lp;
  }

  int cur = 0;
  for (int c=0;c<32;c++){
    __syncthreads();
    if (c < 31){
      const float*        xp = xbase + (size_t)(c+1)*32*D_;
      const unsigned int* pp = pbase + (size_t)(c+1)*32*KG_;
#pragma unroll
      for (int jj=0;jj<8;jj++) v[jj] = xp[(size_t)jj*D_];
#pragma unroll
      for (int jj=0;jj<8;jj++) u[jj] = pp[(size_t)jj*KG_];
    }
#pragma unroll
    for (int j=0;j<4;j++){
      short8 bhi = *(const short8*)&ph[cur][(j*64+lane)*8];
      short8 blo = *(const short8*)&pl[cur][(j*64+lane)*8];
      acc[j] = __builtin_amdgcn_mfma_f32_16x16x32_bf16(ahi, bhi, acc[j], 0,0,0);
      acc[j] = __builtin_amdgcn_mfma_f32_16x16x32_bf16(alo, bhi, acc[j], 0,0,0);
      acc[j] = __builtin_amdgcn_mfma_f32_16x16x32_bf16(ahi, blo, acc[j], 0,0,0);
    }
    if (c < 31){
      cvt8(v, ahi, alo);
      short8 hp, lp;
#pragma unroll
      for (int jj=0;jj<8;jj++){ hp[jj] = (short)(u[jj] & 0xFFFFu); lp[jj] = (short)(u[jj] >> 16); }
      *(short8*)&ph[cur^1][t*8] = hp;
      *(short8*)&pl[cur^1][t*8] = lp;
    }
    cur ^= 1;
  }
#pragma unroll
  for (int j=0;j<4;j++){
    f32x4 vv = acc[j];
    size_t base = (((size_t)ns*B_ + b)*D_ + d0 + w*16 + q*4)*KC_ + j*16 + m;
    vp[base]         = vv[0];
    vp[base +   KC_] = vv[1];
    vp[base + 2*KC_] = vv[2];
    vp[base + 3*KC_] = vv[3];
  }
}

// ---------------- K5a: combine 2 splits + subtract + partial ssq -----------
__global__ __launch_bounds__(256) void k5a(
    const float* __restrict__ vp, const float* __restrict__ c2,
    const float* __restrict__ asum, float* __restrict__ vbuf,
    float* __restrict__ ssq)
{
  __shared__ float red[4][64];
  const int blk = blockIdx.x;
  const int b = blk >> 3, ds = blk & 7;
  const int t = threadIdx.x;
  const int k = t & 63, dg = t >> 6;
  const float av = asum[b*KC_ + k];
  const size_t stride = (size_t)B_*D_*KC_;
  float ss = 0.f;
#pragma unroll
  for (int s=0;s<16;s++){
    int d = ds*64 + dg + 4*s;
    size_t idx = ((size_t)b*D_ + d)*KC_ + k;
    float vv = vp[idx] + vp[idx+stride];
    vv -= c2[d*KC_ + k]*av;
    vbuf[idx] = vv;
    ss += vv*vv;
  }
  red[dg][k] = ss;
  __syncthreads();
  if (t < 64){
    float v = red[0][t] + red[1][t] + red[2][t] + red[3][t];
    atomicAdd(&ssq[b*KC_ + t], v);
  }
}

// ---------------- K5b: norms from ssq, scale, write out (full GPU) ---------
__global__ __launch_bounds__(256) void k5b(
    const float* __restrict__ vbuf, const float* __restrict__ ssq,
    float* __restrict__ out)
{
  __shared__ float invd[64];
  __shared__ float gi_s;
  const int blk = blockIdx.x;
  const int b = blk >> 3, ds = blk & 7;
  const int t = threadIdx.x;
  const int k = t & 63, dg = t >> 6;
  if (t < 64){
    float n2 = ssq[b*KC_ + t];
    float nn = sqrtf(n2);
    float denom = fmaxf(nn, 1e-12f);
    invd[t] = 1.f/denom;
    float ratio = nn/denom;
    float r2 = ratio*ratio;
#pragma unroll
    for (int mm=1;mm<64;mm<<=1) r2 += __shfl_xor(r2, mm);
    if (t==0){
      gi_s = 1.f/fmaxf(sqrtf(r2), 1e-12f);
    }
  }
  __syncthreads();
  const float gik = gi_s * invd[k];
#pragma unroll
  for (int s=0;s<16;s++){
    int d = ds*64 + dg + 4*s;
    size_t idx = ((size_t)b*D_ + d)*KC_ + k;
    out[idx] = vbuf[idx]*gik;
  }
}

extern "C" void kernel_launch(void* const* d_in, const int* in_sizes, int n_in,
                              void* d_out, int out_size, void* d_ws, size_t ws_size,
                              hipStream_t stream)
{
  const float* x     = (const float*)d_in[0];
  const float* cl    = (const float*)d_in[1];
  const float* c2    = (const float*)d_in[2];
  const float* gamma = (const float*)d_in[3];
  const float* beta  = (const float*)d_in[4];
  float* out = (float*)d_out;
  float* ws  = (float*)d_ws;

  // ws (floats): S1[80]@0  S2[80]@80  asum[2048]@160  ssq[2048]@2208
  //   (memset [0,4608))
  //   Bf (ushort 81920 = 40960 floats) @4608
  //   a [M*80] @45568  (p32 in-place after K3; vbuf reuse after K4)
  //   vp [2*B*D*KC] after a
  float* S1    = ws;
  float* S2    = ws + 80;
  float* asum  = ws + 160;
  float* ssq   = ws + 2208;
  unsigned short* Bf = (unsigned short*)(ws + 4608);
  float* a     = ws + 45568;
  float* vp    = a + (size_t)M_*KG_;

  hipMemsetAsync(ws, 0, 4608*sizeof(float), stream);
  k0_prep   <<<40,   256, 0, stream>>>(cl, Bf);
  k1_proj   <<<512,  256, 0, stream>>>(x, (const unsigned int*)Bf, a, S1, S2);
  k3_softmax<<<1024, 256, 0, stream>>>(a, S1, S2, gamma, beta, asum);
  k4_vlad   <<<512,  256, 0, stream>>>(x, (const unsigned int*)a, vp);
  k5a       <<<256,  256, 0, stream>>>(vp, c2, asum, a, ssq);
  k5b       <<<256,  256, 0, stream>>>(a, ssq, out);
}